// Round 7
// baseline (633.199 us; speedup 1.0000x reference)
//
#include <hip/hip_runtime.h>
#include <hip/hip_bf16.h>

// Problem constants (GLA layer): D_MODEL=1024, D_K=D_V=64, H=16, B=4, T=2048
#define DM   1024
#define NH   16
#define TSEQ 2048
#define BBATCH 4
#define MM   (BBATCH*TSEQ)   // 8192 rows of x

typedef unsigned short USH;
typedef __attribute__((ext_vector_type(8))) short bf16x8;
typedef __attribute__((ext_vector_type(4))) float f32x4;

__device__ __forceinline__ USH f2bf(float f) {
  __hip_bfloat16 h = __float2bfloat16(f);
  return __builtin_bit_cast(USH, h);
}
__device__ __forceinline__ float bflo(unsigned u) { return __uint_as_float(u << 16); }
__device__ __forceinline__ float bfhi(unsigned u) { return __uint_as_float(u & 0xffff0000u); }

// async global->LDS, 16B per lane. LDS dst = wave-uniform base + lane*16.
__device__ __forceinline__ void load16_lds(const void* g, void* l) {
  __builtin_amdgcn_global_load_lds(
      (const __attribute__((address_space(1))) unsigned int*)g,
      (__attribute__((address_space(3))) unsigned int*)l, 16, 0, 0);
}

// ---------------- prep: x->bf16 convert + 5 weight transposes + counter zero ----------------
// grid (32,32,6): z<5 = transpose+convert weight z; z==5 = convert x (1024 blocks).
__global__ void prep(const float* __restrict__ x, const float* __restrict__ w0,
                     const float* __restrict__ w1, const float* __restrict__ w2,
                     const float* __restrict__ w3, const float* __restrict__ w4,
                     USH* __restrict__ xb, USH* __restrict__ wcatT,
                     USH* __restrict__ woT, int* __restrict__ cnt) {
  const int z = blockIdx.z;
  const int tid = threadIdx.x;
  if (z == 5) {
    int b = blockIdx.y * 32 + blockIdx.x;
    if (b == 0 && tid < 64) cnt[tid] = 0;  // stitch counters (ws is 0xAA-poisoned)
    size_t base = (size_t)b * 8192 + tid * 4;
#pragma unroll
    for (int it = 0; it < 8; ++it) {
      size_t i = base + (size_t)it * 1024;
      float4 f = *(const float4*)(x + i);
      ushort4 u;
      u.x = f2bf(f.x); u.y = f2bf(f.y); u.z = f2bf(f.z); u.w = f2bf(f.w);
      *(ushort4*)(xb + i) = u;
    }
    return;
  }
  const float* src = (z == 0) ? w0 : (z == 1) ? w1 : (z == 2) ? w2 : (z == 3) ? w3 : w4;
  USH* dst = (z < 4) ? (wcatT + (size_t)z * 1024 * 1024) : woT;
  __shared__ float tile[32][33];
  const int tx = tid & 31, ty = tid >> 5;
  int xx = blockIdx.x * 32 + tx;
  int yy = blockIdx.y * 32;
  for (int j = ty; j < 32; j += 8)
    tile[j][tx] = src[(size_t)(yy + j) * 1024 + xx];
  __syncthreads();
  int x2 = blockIdx.y * 32 + tx;
  int y2 = blockIdx.x * 32;
  for (int j = ty; j < 32; j += 8)
    dst[(size_t)(y2 + j) * 1024 + x2] = f2bf(tile[tx][j]);
}

// ---------------- MFMA GEMM: C(MxN) = A(MxK) * B^T(NxK), bf16 in, f32 acc ----------------
// XOR-swizzled LDS staging (global-side swizzle, undone at ds_read) — R5-verified.
// LDS capped at 32768 B -> 5 blocks/CU.
template <int EPI>
__global__ __launch_bounds__(256, 2) void gemm_bt(
    const USH* __restrict__ A, const USH* __restrict__ B, int K,
    USH* __restrict__ q_out, USH* __restrict__ k_out, USH* __restrict__ v_out,
    USH* __restrict__ a_out, const float* __restrict__ bias,
    float* __restrict__ c_out) {
  __shared__ __align__(16) char smem[32768];
  short* As = (short*)smem;
  short* Bs = (short*)(smem + 16384);
  const int tid = threadIdx.x;
  const int wave = tid >> 6;
  const int lane = tid & 63;
  const int bm = blockIdx.y, bn = blockIdx.x;
  const int wm = (wave >> 1) * 64;
  const int wn = (wave & 1) * 64;

  f32x4 acc[4][4];
#pragma unroll
  for (int i = 0; i < 4; i++)
#pragma unroll
    for (int j = 0; j < 4; j++) acc[i][j] = (f32x4){0.f, 0.f, 0.f, 0.f};

  const int srow = wave * 8 + (lane >> 3);
  const int scol = ((lane & 7) ^ (lane >> 3)) * 8;  // swizzled global k-offset

  for (int k0 = 0; k0 < K; k0 += 64) {
#pragma unroll
    for (int i = 0; i < 4; ++i) {
      int row = i * 32 + srow;
      const USH* ga = A + (size_t)(bm * 128 + row) * K + k0 + scol;
      const USH* gb = B + (size_t)(bn * 128 + row) * K + k0 + scol;
      int lofs = __builtin_amdgcn_readfirstlane((i * 32 + wave * 8) * 64);
      load16_lds(ga, (void*)(As + lofs));
      load16_lds(gb, (void*)(Bs + lofs));
    }
    __syncthreads();
    const int m16 = lane & 15;
    const int sw = lane & 7;
    const int kc = lane >> 4;
#pragma unroll
    for (int ks = 0; ks < 64; ks += 32) {
      bf16x8 af[4], bf[4];
#pragma unroll
      for (int i = 0; i < 4; i++)
        af[i] = *(const bf16x8*)&As[(wm + i * 16 + m16) * 64 + ((((ks >> 3) + kc) ^ sw) << 3)];
#pragma unroll
      for (int j = 0; j < 4; j++)
        bf[j] = *(const bf16x8*)&Bs[(wn + j * 16 + m16) * 64 + ((((ks >> 3) + kc) ^ sw) << 3)];
#pragma unroll
      for (int i = 0; i < 4; i++)
#pragma unroll
        for (int j = 0; j < 4; j++)
          acc[i][j] = __builtin_amdgcn_mfma_f32_16x16x32_bf16(af[i], bf[j], acc[i][j], 0, 0, 0);
    }
    __syncthreads();
  }

  // epilogue. C/D layout: col = lane&15, row = (lane>>4)*4 + reg  [m89-verified]
  const int r0 = (lane >> 4) * 4;
  const int cc = lane & 15;
  if (EPI == 1) {
    USH* ep = (USH*)smem;  // [128][128] bf16/u16 (no pad; one-time store conflicts OK)
    const int which = bn >> 3;  // block-uniform output select
    float bj[4];
    if (which == 3) {
#pragma unroll
      for (int j = 0; j < 4; j++) bj[j] = bias[(bn & 7) * 128 + wn + j * 16 + cc];
    }
#pragma unroll
    for (int i = 0; i < 4; i++)
#pragma unroll
      for (int j = 0; j < 4; j++)
#pragma unroll
        for (int r = 0; r < 4; r++) {
          float val = acc[i][j][r];
          USH o;
          if (which == 3) {
            float s = 1.0f / (1.0f + __expf(-(val + bj[j])));
            o = (USH)(s * 65535.0f + 0.5f);  // u16 gate: rel err ~8e-6
          } else {
            o = f2bf(val);
          }
          ep[(wm + i * 16 + r0 + r) * 128 + wn + j * 16 + cc] = o;
        }
    __syncthreads();
    USH* dst = (which == 0) ? q_out : (which == 1) ? k_out : (which == 2) ? v_out : a_out;
    const int rr = tid >> 4, ccol = (tid & 15) * 8;
#pragma unroll
    for (int it = 0; it < 8; ++it) {
      int row = it * 16 + rr;
      uint4 vd = *(const uint4*)&ep[row * 128 + ccol];
      *(uint4*)(dst + (size_t)(bm * 128 + row) * 1024 + (bn & 7) * 128 + ccol) = vd;
    }
  } else {
    float* epf = (float*)smem;  // [64][128] f32, two 64-row halves
#pragma unroll
    for (int h = 0; h < 2; ++h) {
      if (wm == h * 64) {
#pragma unroll
        for (int i = 0; i < 4; i++)
#pragma unroll
          for (int j = 0; j < 4; j++)
#pragma unroll
            for (int r = 0; r < 4; r++)
              epf[(i * 16 + r0 + r) * 128 + wn + j * 16 + cc] = acc[i][j][r];
      }
      __syncthreads();
      const int rr = tid >> 5, c4 = (tid & 31) * 4;
#pragma unroll
      for (int it = 0; it < 8; ++it) {
        int row = it * 8 + rr;
        float4 vd = *(const float4*)&epf[row * 128 + c4];
        *(float4*)(c_out + (size_t)(bm * 128 + h * 64 + row) * 1024 + bn * 128 + c4) = vd;
      }
      if (h == 0) __syncthreads();
    }
  }
}

// ---------------- Pass A: per-chunk MFMA scan (C=64) + fused stitch ----------------
// Grid 2048 = 64 bh x 32 chunks, 256 threads (4 waves).
// P = (Q*A) @ (K/A)^T masked causal; O_intra = P@V; S_loc^T = V^T@Khat (v-major);
// writes q~ in-place to qb. Last block per bh (atomic counter) runs the stitch:
// sequentially over 32 chunks, writes S_start^T in bf16 IN-PLACE into each SB slot
// (barrier between slot read and bf16 overwrite), carrying prefix in registers.
__global__ __launch_bounds__(256, 3) void gla_chunk(
    USH* __restrict__ qb, const USH* __restrict__ kb, const USH* __restrict__ vb,
    const USH* __restrict__ au, USH* __restrict__ ob,
    float* __restrict__ SB, float* __restrict__ Dc, int* __restrict__ cnt) {
  const int bh = blockIdx.x >> 5, ch = blockIdx.x & 31;
  const size_t base = (size_t)(bh >> 4) * TSEQ * 1024 + (size_t)(bh & 15) * 64;
  const int row0 = ch * 64;
  const int tid = threadIdx.x, wv = tid >> 6, ln = tid & 63;

  __shared__ __align__(16) char smem[54528];
  __shared__ int lastflag;
  USH* Qs  = (USH*)smem;             // [64][72] bf16 q~
  USH* Ks  = (USH*)(smem + 9216);    // [64][72] bf16 k~ (rows s)
  USH* Kht = (USH*)(smem + 18432);   // [64][72] bf16 k^ transposed (rows k)
  USH* Vt  = (USH*)(smem + 27648);   // [64][72] bf16 V transposed (rows v)
  float* psum = (float*)(smem + 27648);  // aliases Vt head; dead before Vt written
  USH* Ps  = (USH*)(smem + 36864);   // [64][72] masked P, bf16 (aliases Ag)
  USH* so  = (USH*)(smem + 46080);   // [64][66] O_intra bf16 (aliases Ag tail)
  float* Ag = (float*)(smem + 36864); // [64][65] fp32 cumprod; dead before Ps/so

  // ---- phase 1: per-column cumulative product of gates (fp32) ----
  {
    const int c1 = tid & 63, sg = tid >> 6;
    float lp[16], p = 1.f;
#pragma unroll
    for (int r = 0; r < 16; ++r) {
      float a = (float)au[base + (size_t)(row0 + sg * 16 + r) * 1024 + c1] * (1.f / 65535.f);
      p *= a;
      lp[r] = p;
    }
    psum[sg * 64 + c1] = p;
    __syncthreads();
    float pre = 1.f;
    for (int s2 = 0; s2 < sg; ++s2) pre *= psum[s2 * 64 + c1];
#pragma unroll
    for (int r = 0; r < 16; ++r) Ag[(sg * 16 + r) * 65 + c1] = pre * lp[r];
  }
  __syncthreads();
  if (tid < 64) Dc[((size_t)bh * 32 + ch) * 64 + tid] = Ag[63 * 65 + tid];

  // ---- phase 2: build q~, k~, k^T, V^T in LDS; write q~ back to qb ----
  {
    const int rr = tid >> 4, cg = (tid & 15) * 4;
    float AC[4];
#pragma unroll
    for (int i = 0; i < 4; i++) AC[i] = Ag[63 * 65 + cg + i];
#pragma unroll
    for (int j = 0; j < 4; ++j) {
      int row = rr + j * 16;
      size_t g = base + (size_t)(row0 + row) * 1024 + cg;
      uint2 qv = *(const uint2*)(qb + g);
      uint2 kv = *(const uint2*)(kb + g);
      uint2 vv = *(const uint2*)(vb + g);
      float A0 = Ag[row * 65 + cg], A1 = Ag[row * 65 + cg + 1];
      float A2 = Ag[row * 65 + cg + 2], A3 = Ag[row * 65 + cg + 3];
      ushort4 qt;
      qt.x = f2bf(bflo(qv.x) * A0); qt.y = f2bf(bfhi(qv.x) * A1);
      qt.z = f2bf(bflo(qv.y) * A2); qt.w = f2bf(bfhi(qv.y) * A3);
      *(ushort4*)&Qs[row * 72 + cg] = qt;
      *(ushort4*)(qb + g) = qt;  // for pass C
      float R0 = 1.f / A0, R1 = 1.f / A1, R2 = 1.f / A2, R3 = 1.f / A3;
      float kt0 = bflo(kv.x) * R0, kt1 = bfhi(kv.x) * R1;
      float kt2 = bflo(kv.y) * R2, kt3 = bfhi(kv.y) * R3;
      ushort4 kt;
      kt.x = f2bf(kt0); kt.y = f2bf(kt1); kt.z = f2bf(kt2); kt.w = f2bf(kt3);
      *(ushort4*)&Ks[row * 72 + cg] = kt;
      Kht[(cg + 0) * 72 + row] = f2bf(kt0 * AC[0]);
      Kht[(cg + 1) * 72 + row] = f2bf(kt1 * AC[1]);
      Kht[(cg + 2) * 72 + row] = f2bf(kt2 * AC[2]);
      Kht[(cg + 3) * 72 + row] = f2bf(kt3 * AC[3]);
      Vt[(cg + 0) * 72 + row] = (USH)(vv.x & 0xffff);
      Vt[(cg + 1) * 72 + row] = (USH)(vv.x >> 16);
      Vt[(cg + 2) * 72 + row] = (USH)(vv.y & 0xffff);
      Vt[(cg + 3) * 72 + row] = (USH)(vv.y >> 16);
    }
  }
  __syncthreads();

  const int q4 = (ln >> 4) * 4, cc = ln & 15, m16 = ln & 15;

  // ---- MFMA1: P = Q~ @ K~^T ----
  f32x4 pc[4];
#pragma unroll
  for (int n = 0; n < 4; n++) pc[n] = (f32x4){0.f, 0.f, 0.f, 0.f};
#pragma unroll
  for (int ks = 0; ks < 64; ks += 32) {
    bf16x8 aq = *(const bf16x8*)&Qs[(wv * 16 + m16) * 72 + ks + (ln >> 4) * 8];
#pragma unroll
    for (int n = 0; n < 4; ++n) {
      bf16x8 bk = *(const bf16x8*)&Ks[(n * 16 + m16) * 72 + ks + (ln >> 4) * 8];
      pc[n] = __builtin_amdgcn_mfma_f32_16x16x32_bf16(aq, bk, pc[n], 0, 0, 0);
    }
  }
#pragma unroll
  for (int n = 0; n < 4; ++n) {
    int s = n * 16 + cc;
#pragma unroll
    for (int r = 0; r < 4; ++r) {
      int t = wv * 16 + q4 + r;
      Ps[t * 72 + s] = f2bf(s <= t ? pc[n][r] : 0.f);
    }
  }

  // ---- MFMA3 (transposed): S_loc^T[v][k] = sum_s V^T[v][s] * Khat^T[k][s] ----
  f32x4 sc[4];
#pragma unroll
  for (int n = 0; n < 4; n++) sc[n] = (f32x4){0.f, 0.f, 0.f, 0.f};
#pragma unroll
  for (int ks = 0; ks < 64; ks += 32) {
    bf16x8 av = *(const bf16x8*)&Vt[(wv * 16 + m16) * 72 + ks + (ln >> 4) * 8];
#pragma unroll
    for (int n = 0; n < 4; ++n) {
      bf16x8 bk2 = *(const bf16x8*)&Kht[(n * 16 + m16) * 72 + ks + (ln >> 4) * 8];
      sc[n] = __builtin_amdgcn_mfma_f32_16x16x32_bf16(av, bk2, sc[n], 0, 0, 0);
    }
  }
  {
    float* sbp = SB + ((size_t)bh * 32 + ch) * 4096;  // [v][k] f32
#pragma unroll
    for (int n = 0; n < 4; ++n)
#pragma unroll
      for (int r = 0; r < 4; ++r)
        sbp[(wv * 16 + q4 + r) * 64 + n * 16 + cc] = sc[n][r];
  }
  __syncthreads();  // Ps visible

  // ---- MFMA2: O_intra = P @ V ----
  f32x4 oc[4];
#pragma unroll
  for (int n = 0; n < 4; n++) oc[n] = (f32x4){0.f, 0.f, 0.f, 0.f};
#pragma unroll
  for (int ks = 0; ks < 64; ks += 32) {
    bf16x8 ap = *(const bf16x8*)&Ps[(wv * 16 + m16) * 72 + ks + (ln >> 4) * 8];
#pragma unroll
    for (int n = 0; n < 4; ++n) {
      bf16x8 bv = *(const bf16x8*)&Vt[(n * 16 + m16) * 72 + ks + (ln >> 4) * 8];
      oc[n] = __builtin_amdgcn_mfma_f32_16x16x32_bf16(ap, bv, oc[n], 0, 0, 0);
    }
  }
#pragma unroll
  for (int n = 0; n < 4; ++n)
#pragma unroll
    for (int r = 0; r < 4; ++r)
      so[(wv * 16 + q4 + r) * 66 + n * 16 + cc] = f2bf(oc[n][r]);
  __syncthreads();
#pragma unroll
  for (int j = 0; j < 4; ++j) {
    int row = (tid >> 4) + j * 16, cg = (tid & 15) * 4;
    unsigned a = *(const unsigned*)&so[row * 66 + cg];
    unsigned b = *(const unsigned*)&so[row * 66 + cg + 2];
    size_t g = base + (size_t)(row0 + row) * 1024 + cg;
    *(unsigned*)(ob + g) = a;
    *(unsigned*)(ob + g + 2) = b;
  }

  // ---- fused stitch: last block of this bh converts S_loc^T -> S_start^T (bf16, in place)
  __threadfence();  // SB/Dc stores visible device-wide before the count
  if (tid == 0) {
    int old = atomicAdd(&cnt[bh], 1);
    lastflag = (old == 31) ? 1 : 0;
  }
  __syncthreads();
  if (lastflag) {
    __threadfence();  // acquire: all 32 blocks' SB/Dc writes visible
    const int v = tid >> 2, kq = (tid & 3) * 16;
    float s[16];
#pragma unroll
    for (int i = 0; i < 16; i++) s[i] = 0.f;
    for (int c = 0; c < 32; ++c) {
      float* slot = SB + ((size_t)bh * 32 + c) * 4096;
      float4 l0 = *(float4*)(slot + v * 64 + kq + 0);
      float4 l1 = *(float4*)(slot + v * 64 + kq + 4);
      float4 l2 = *(float4*)(slot + v * 64 + kq + 8);
      float4 l3 = *(float4*)(slot + v * 64 + kq + 12);
      const float* dp = Dc + ((size_t)bh * 32 + c) * 64 + kq;
      float4 d0 = *(const float4*)(dp + 0), d1 = *(const float4*)(dp + 4);
      float4 d2 = *(const float4*)(dp + 8), d3 = *(const float4*)(dp + 12);
      __syncthreads();  // all reads of slot c done before bf16 overwrite
      USH* up = (USH*)slot;  // S_start^T bf16 [64][64] in slot's first 8 KB
      uint4 o0, o1;
      o0.x = (unsigned)f2bf(s[0]) | ((unsigned)f2bf(s[1]) << 16);
      o0.y = (unsigned)f2bf(s[2]) | ((unsigned)f2bf(s[3]) << 16);
      o0.z = (unsigned)f2bf(s[4]) | ((unsigned)f2bf(s[5]) << 16);
      o0.w = (unsigned)f2bf(s[6]) | ((unsigned)f2bf(s[7]) << 16);
      o1.x = (unsigned)f2bf(s[8]) | ((unsigned)f2bf(s[9]) << 16);
      o1.y = (unsigned)f2bf(s[10]) | ((unsigned)f2bf(s[11]) << 16);
      o1.z = (unsigned)f2bf(s[12]) | ((unsigned)f2bf(s[13]) << 16);
      o1.w = (unsigned)f2bf(s[14]) | ((unsigned)f2bf(s[15]) << 16);
      *(uint4*)(up + v * 64 + kq + 0) = o0;
      *(uint4*)(up + v * 64 + kq + 8) = o1;
      s[0] = fmaf(d0.x, s[0], l0.x);  s[1] = fmaf(d0.y, s[1], l0.y);
      s[2] = fmaf(d0.z, s[2], l0.z);  s[3] = fmaf(d0.w, s[3], l0.w);
      s[4] = fmaf(d1.x, s[4], l1.x);  s[5] = fmaf(d1.y, s[5], l1.y);
      s[6] = fmaf(d1.z, s[6], l1.z);  s[7] = fmaf(d1.w, s[7], l1.w);
      s[8] = fmaf(d2.x, s[8], l2.x);  s[9] = fmaf(d2.y, s[9], l2.y);
      s[10] = fmaf(d2.z, s[10], l2.z); s[11] = fmaf(d2.w, s[11], l2.w);
      s[12] = fmaf(d3.x, s[12], l3.x); s[13] = fmaf(d3.y, s[13], l3.y);
      s[14] = fmaf(d3.z, s[14], l3.z); s[15] = fmaf(d3.w, s[15], l3.w);
    }
  }
}

// ---------------- Pass C: o += q~ @ S_start (MFMA), chunks 1..31 ----------------
// S_start^T bf16 read from SB slot heads (written by the fused stitch).
__global__ __launch_bounds__(256, 4) void gla_corr(
    const USH* __restrict__ qtb, const float* __restrict__ SB, USH* __restrict__ ob) {
  const int bh = blockIdx.y, chn = blockIdx.x + 1;
  const size_t base = (size_t)(bh >> 4) * TSEQ * 1024 + (size_t)(bh & 15) * 64;
  const int trow0 = chn * 64;
  const int tid = threadIdx.x, wv = tid >> 6, ln = tid & 63;
  __shared__ USH qs[64 * 72];
  __shared__ USH sbt[64 * 72];   // S_start^T bf16 [v][k]
  __shared__ float sof[64 * 68]; // o_inter f32 [t][v]
  const USH* sp = (const USH*)(SB + ((size_t)bh * 32 + chn) * 4096);
#pragma unroll
  for (int j = 0; j < 4; ++j) {
    int i = tid + 256 * j;
    int row = i >> 4, cg = (i & 15) * 4;
    *(uint2*)&qs[row * 72 + cg] = *(const uint2*)(qtb + base + (size_t)(trow0 + row) * 1024 + cg);
    *(uint2*)&sbt[row * 72 + cg] = *(const uint2*)(sp + row * 64 + cg);
  }
  __syncthreads();
  const int m16 = ln & 15, q4 = (ln >> 4) * 4, cc = ln & 15;
  f32x4 oc[4];
#pragma unroll
  for (int n = 0; n < 4; n++) oc[n] = (f32x4){0.f, 0.f, 0.f, 0.f};
#pragma unroll
  for (int ks = 0; ks < 64; ks += 32) {
    bf16x8 aq = *(const bf16x8*)&qs[(wv * 16 + m16) * 72 + ks + (ln >> 4) * 8];
#pragma unroll
    for (int n = 0; n < 4; ++n) {
      bf16x8 bv = *(const bf16x8*)&sbt[(n * 16 + m16) * 72 + ks + (ln >> 4) * 8];
      oc[n] = __builtin_amdgcn_mfma_f32_16x16x32_bf16(aq, bv, oc[n], 0, 0, 0);
    }
  }
#pragma unroll
  for (int n = 0; n < 4; ++n)
#pragma unroll
    for (int r = 0; r < 4; ++r)
      sof[(wv * 16 + q4 + r) * 68 + n * 16 + cc] = oc[n][r];
  __syncthreads();
  const int row = tid >> 2, vg = (tid & 3) * 16;
  float4 a0 = *(const float4*)&sof[row * 68 + vg + 0];
  float4 a1 = *(const float4*)&sof[row * 68 + vg + 4];
  float4 a2 = *(const float4*)&sof[row * 68 + vg + 8];
  float4 a3 = *(const float4*)&sof[row * 68 + vg + 12];
  USH* op = ob + base + (size_t)(trow0 + row) * 1024 + vg;
  float ac[16] = {a0.x, a0.y, a0.z, a0.w, a1.x, a1.y, a1.z, a1.w,
                  a2.x, a2.y, a2.z, a2.w, a3.x, a3.y, a3.z, a3.w};
#pragma unroll
  for (int g = 0; g < 4; ++g) {
    ushort4 o4 = *(ushort4*)(op + g * 4);
    o4.x = f2bf(bflo((unsigned)o4.x) + ac[g * 4 + 0]);
    o4.y = f2bf(bflo((unsigned)o4.y) + ac[g * 4 + 1]);
    o4.z = f2bf(bflo((unsigned)o4.z) + ac[g * 4 + 2]);
    o4.w = f2bf(bflo((unsigned)o4.w) + ac[g * 4 + 3]);
    *(ushort4*)(op + g * 4) = o4;
  }
}

extern "C" void kernel_launch(void* const* d_in, const int* in_sizes, int n_in,
                              void* d_out, int out_size, void* d_ws, size_t ws_size,
                              hipStream_t stream) {
  const float* x  = (const float*)d_in[0];
  const float* Wq = (const float*)d_in[1];
  const float* Wk = (const float*)d_in[2];
  const float* Wv = (const float*)d_in[3];
  const float* Wg = (const float*)d_in[4];
  const float* bg = (const float*)d_in[5];
  const float* Wo = (const float*)d_in[6];
  float* out = (float*)d_out;

  // workspace layout (~114.5 MiB; SB's first 8 MiB doubles as WcatT — dead after GEMM1)
  char* ws = (char*)d_ws;
  size_t off = 0;
  auto alloc = [&](size_t bytes) {
    char* p = ws + off;
    off += (bytes + 255) & ~(size_t)255;
    return p;
  };
  USH* xb   = (USH*)alloc((size_t)MM * DM * 2);          // 16 MiB (reused as ob)
  USH* WoT  = (USH*)alloc((size_t)1024 * 1024 * 2);      // 2 MiB
  USH* qb   = (USH*)alloc((size_t)MM * DM * 2);          // 16 MiB
  USH* kb   = (USH*)alloc((size_t)MM * DM * 2);          // 16 MiB
  USH* vb   = (USH*)alloc((size_t)MM * DM * 2);          // 16 MiB
  USH* au   = (USH*)alloc((size_t)MM * DM * 2);          // 16 MiB u16 gate
  float* Dc = (float*)alloc((size_t)64 * 32 * 64 * 4);   // 512 KiB chunk decay (FULLY used: idx 0..131071)
  int* cnt  = (int*)alloc(64 * sizeof(int));             // stitch counters — OWN allocation
                                                         // (R6 bug: carved from Dc -> clobbered)
  float* SB = (float*)alloc((size_t)64 * 32 * 4096 * 4); // 32 MiB chunk states
  USH* WcatT = (USH*)SB;                                 // aliased (GEMM1 only)
  USH* ob = xb;                                          // xb dead after GEMM1

  // prep: x->bf16, 5 weight transposes, zero stitch counters (1 launch)
  prep<<<dim3(32, 32, 6), 256, 0, stream>>>(x, Wq, Wk, Wv, Wg, Wo, xb, WcatT, WoT, cnt);
  // fused QKV+gate GEMM: (8192x1024) x (1024x4096)
  gemm_bt<1><<<dim3(32, 64), 256, 0, stream>>>(xb, WcatT, 1024, qb, kb, vb, au, bg, nullptr);
  // chunked MFMA scan + fused stitch (last block per bh)
  gla_chunk<<<2048, 256, 0, stream>>>(qb, kb, vb, au, ob, SB, Dc, cnt);
  // cross-chunk correction (MFMA, bf16 S_start^T)
  gla_corr<<<dim3(31, 64), 256, 0, stream>>>(qb, SB, ob);
  // output projection: (8192x1024) x (1024x1024) -> f32 d_out
  gemm_bt<0><<<dim3(8, 64), 256, 0, stream>>>(ob, WoT, 1024, nullptr, nullptr, nullptr,
                                              nullptr, nullptr, out);
}

// Round 8
// 264.038 us; speedup vs baseline: 2.3981x; 2.3981x over previous
//
#include <hip/hip_runtime.h>
#include <hip/hip_bf16.h>

// Problem constants (GLA layer): D_MODEL=1024, D_K=D_V=64, H=16, B=4, T=2048
#define DM   1024
#define NH   16
#define TSEQ 2048
#define BBATCH 4
#define MM   (BBATCH*TSEQ)   // 8192 rows of x

typedef unsigned short USH;
typedef __attribute__((ext_vector_type(8))) short bf16x8;
typedef __attribute__((ext_vector_type(4))) float f32x4;

__device__ __forceinline__ USH f2bf(float f) {
  __hip_bfloat16 h = __float2bfloat16(f);
  return __builtin_bit_cast(USH, h);
}
__device__ __forceinline__ float bflo(unsigned u) { return __uint_as_float(u << 16); }
__device__ __forceinline__ float bfhi(unsigned u) { return __uint_as_float(u & 0xffff0000u); }

// async global->LDS, 16B per lane. LDS dst = wave-uniform base + lane*16.
__device__ __forceinline__ void load16_lds(const void* g, void* l) {
  __builtin_amdgcn_global_load_lds(
      (const __attribute__((address_space(1))) unsigned int*)g,
      (__attribute__((address_space(3))) unsigned int*)l, 16, 0, 0);
}

// ---------------- prep: x->bf16 convert + 5 weight transposes ----------------
// grid (32,32,6): z<5 = transpose+convert weight z; z==5 = convert x (1024 blocks).
__global__ void prep(const float* __restrict__ x, const float* __restrict__ w0,
                     const float* __restrict__ w1, const float* __restrict__ w2,
                     const float* __restrict__ w3, const float* __restrict__ w4,
                     USH* __restrict__ xb, USH* __restrict__ wcatT,
                     USH* __restrict__ woT) {
  const int z = blockIdx.z;
  const int tid = threadIdx.x;
  if (z == 5) {
    int b = blockIdx.y * 32 + blockIdx.x;
    size_t base = (size_t)b * 8192 + tid * 4;
#pragma unroll
    for (int it = 0; it < 8; ++it) {
      size_t i = base + (size_t)it * 1024;
      float4 f = *(const float4*)(x + i);
      ushort4 u;
      u.x = f2bf(f.x); u.y = f2bf(f.y); u.z = f2bf(f.z); u.w = f2bf(f.w);
      *(ushort4*)(xb + i) = u;
    }
    return;
  }
  const float* src = (z == 0) ? w0 : (z == 1) ? w1 : (z == 2) ? w2 : (z == 3) ? w3 : w4;
  USH* dst = (z < 4) ? (wcatT + (size_t)z * 1024 * 1024) : woT;
  __shared__ float tile[32][33];
  const int tx = tid & 31, ty = tid >> 5;
  int xx = blockIdx.x * 32 + tx;
  int yy = blockIdx.y * 32;
  for (int j = ty; j < 32; j += 8)
    tile[j][tx] = src[(size_t)(yy + j) * 1024 + xx];
  __syncthreads();
  int x2 = blockIdx.y * 32 + tx;
  int y2 = blockIdx.x * 32;
  for (int j = ty; j < 32; j += 8)
    dst[(size_t)(y2 + j) * 1024 + x2] = f2bf(tile[tx][j]);
}

// ---------------- MFMA GEMM: C(MxN) = A(MxK) * B^T(NxK), bf16 in, f32 acc ----------------
// XOR-swizzled LDS staging (global-side swizzle, undone at ds_read) — R5-verified.
// LDS capped at 32768 B -> 5 blocks/CU.
template <int EPI>
__global__ __launch_bounds__(256, 2) void gemm_bt(
    const USH* __restrict__ A, const USH* __restrict__ B, int K,
    USH* __restrict__ q_out, USH* __restrict__ k_out, USH* __restrict__ v_out,
    USH* __restrict__ a_out, const float* __restrict__ bias,
    float* __restrict__ c_out) {
  __shared__ __align__(16) char smem[32768];
  short* As = (short*)smem;
  short* Bs = (short*)(smem + 16384);
  const int tid = threadIdx.x;
  const int wave = tid >> 6;
  const int lane = tid & 63;
  const int bm = blockIdx.y, bn = blockIdx.x;
  const int wm = (wave >> 1) * 64;
  const int wn = (wave & 1) * 64;

  f32x4 acc[4][4];
#pragma unroll
  for (int i = 0; i < 4; i++)
#pragma unroll
    for (int j = 0; j < 4; j++) acc[i][j] = (f32x4){0.f, 0.f, 0.f, 0.f};

  const int srow = wave * 8 + (lane >> 3);
  const int scol = ((lane & 7) ^ (lane >> 3)) * 8;  // swizzled global k-offset

  for (int k0 = 0; k0 < K; k0 += 64) {
#pragma unroll
    for (int i = 0; i < 4; ++i) {
      int row = i * 32 + srow;
      const USH* ga = A + (size_t)(bm * 128 + row) * K + k0 + scol;
      const USH* gb = B + (size_t)(bn * 128 + row) * K + k0 + scol;
      int lofs = __builtin_amdgcn_readfirstlane((i * 32 + wave * 8) * 64);
      load16_lds(ga, (void*)(As + lofs));
      load16_lds(gb, (void*)(Bs + lofs));
    }
    __syncthreads();
    const int m16 = lane & 15;
    const int sw = lane & 7;
    const int kc = lane >> 4;
#pragma unroll
    for (int ks = 0; ks < 64; ks += 32) {
      bf16x8 af[4], bf[4];
#pragma unroll
      for (int i = 0; i < 4; i++)
        af[i] = *(const bf16x8*)&As[(wm + i * 16 + m16) * 64 + ((((ks >> 3) + kc) ^ sw) << 3)];
#pragma unroll
      for (int j = 0; j < 4; j++)
        bf[j] = *(const bf16x8*)&Bs[(wn + j * 16 + m16) * 64 + ((((ks >> 3) + kc) ^ sw) << 3)];
#pragma unroll
      for (int i = 0; i < 4; i++)
#pragma unroll
        for (int j = 0; j < 4; j++)
          acc[i][j] = __builtin_amdgcn_mfma_f32_16x16x32_bf16(af[i], bf[j], acc[i][j], 0, 0, 0);
    }
    __syncthreads();
  }

  // epilogue. C/D layout: col = lane&15, row = (lane>>4)*4 + reg  [m89-verified]
  const int r0 = (lane >> 4) * 4;
  const int cc = lane & 15;
  if (EPI == 1) {
    USH* ep = (USH*)smem;  // [128][128] bf16/u16 (no pad; one-time store conflicts OK)
    const int which = bn >> 3;  // block-uniform output select
    float bj[4];
    if (which == 3) {
#pragma unroll
      for (int j = 0; j < 4; j++) bj[j] = bias[(bn & 7) * 128 + wn + j * 16 + cc];
    }
#pragma unroll
    for (int i = 0; i < 4; i++)
#pragma unroll
      for (int j = 0; j < 4; j++)
#pragma unroll
        for (int r = 0; r < 4; r++) {
          float val = acc[i][j][r];
          USH o;
          if (which == 3) {
            float s = 1.0f / (1.0f + __expf(-(val + bj[j])));
            o = (USH)(s * 65535.0f + 0.5f);  // u16 gate: rel err ~8e-6
          } else {
            o = f2bf(val);
          }
          ep[(wm + i * 16 + r0 + r) * 128 + wn + j * 16 + cc] = o;
        }
    __syncthreads();
    USH* dst = (which == 0) ? q_out : (which == 1) ? k_out : (which == 2) ? v_out : a_out;
    const int rr = tid >> 4, ccol = (tid & 15) * 8;
#pragma unroll
    for (int it = 0; it < 8; ++it) {
      int row = it * 16 + rr;
      uint4 vd = *(const uint4*)&ep[row * 128 + ccol];
      *(uint4*)(dst + (size_t)(bm * 128 + row) * 1024 + (bn & 7) * 128 + ccol) = vd;
    }
  } else {
    float* epf = (float*)smem;  // [64][128] f32, two 64-row halves
#pragma unroll
    for (int h = 0; h < 2; ++h) {
      if (wm == h * 64) {
#pragma unroll
        for (int i = 0; i < 4; i++)
#pragma unroll
          for (int j = 0; j < 4; j++)
#pragma unroll
            for (int r = 0; r < 4; r++)
              epf[(i * 16 + r0 + r) * 128 + wn + j * 16 + cc] = acc[i][j][r];
      }
      __syncthreads();
      const int rr = tid >> 5, c4 = (tid & 31) * 4;
#pragma unroll
      for (int it = 0; it < 8; ++it) {
        int row = it * 8 + rr;
        float4 vd = *(const float4*)&epf[row * 128 + c4];
        *(float4*)(c_out + (size_t)(bm * 128 + h * 64 + row) * 1024 + bn * 128 + c4) = vd;
      }
      if (h == 0) __syncthreads();
    }
  }
}

// ---------------- Pass A: per-chunk MFMA scan (C=64) ----------------
// Grid 2048 = 64 bh x 32 chunks, 256 threads (4 waves).
// P = (Q*A) @ (K/A)^T masked causal; O_intra = P@V; S_loc^T = V^T@Khat (v-major);
// writes q~ in-place to qb. NO cross-block sync here — R7 showed 2048 device-scope
// threadfences cost ~440 µs (per-XCD L2 writeback storm); the kernel boundary is
// the cheap way to order chunk -> stitch.
__global__ __launch_bounds__(256, 3) void gla_chunk(
    USH* __restrict__ qb, const USH* __restrict__ kb, const USH* __restrict__ vb,
    const USH* __restrict__ au, USH* __restrict__ ob,
    float* __restrict__ SB, float* __restrict__ Dc) {
  const int bh = blockIdx.x >> 5, ch = blockIdx.x & 31;
  const size_t base = (size_t)(bh >> 4) * TSEQ * 1024 + (size_t)(bh & 15) * 64;
  const int row0 = ch * 64;
  const int tid = threadIdx.x, wv = tid >> 6, ln = tid & 63;

  __shared__ __align__(16) char smem[54528];
  USH* Qs  = (USH*)smem;             // [64][72] bf16 q~
  USH* Ks  = (USH*)(smem + 9216);    // [64][72] bf16 k~ (rows s)
  USH* Kht = (USH*)(smem + 18432);   // [64][72] bf16 k^ transposed (rows k)
  USH* Vt  = (USH*)(smem + 27648);   // [64][72] bf16 V transposed (rows v)
  float* psum = (float*)(smem + 27648);  // aliases Vt head; dead before Vt written
  USH* Ps  = (USH*)(smem + 36864);   // [64][72] masked P, bf16 (aliases Ag)
  USH* so  = (USH*)(smem + 46080);   // [64][66] O_intra bf16 (aliases Ag tail)
  float* Ag = (float*)(smem + 36864); // [64][65] fp32 cumprod; dead before Ps/so

  // ---- phase 1: per-column cumulative product of gates (fp32) ----
  {
    const int c1 = tid & 63, sg = tid >> 6;
    float lp[16], p = 1.f;
#pragma unroll
    for (int r = 0; r < 16; ++r) {
      float a = (float)au[base + (size_t)(row0 + sg * 16 + r) * 1024 + c1] * (1.f / 65535.f);
      p *= a;
      lp[r] = p;
    }
    psum[sg * 64 + c1] = p;
    __syncthreads();
    float pre = 1.f;
    for (int s2 = 0; s2 < sg; ++s2) pre *= psum[s2 * 64 + c1];
#pragma unroll
    for (int r = 0; r < 16; ++r) Ag[(sg * 16 + r) * 65 + c1] = pre * lp[r];
  }
  __syncthreads();
  if (tid < 64) Dc[((size_t)bh * 32 + ch) * 64 + tid] = Ag[63 * 65 + tid];

  // ---- phase 2: build q~, k~, k^T, V^T in LDS; write q~ back to qb ----
  {
    const int rr = tid >> 4, cg = (tid & 15) * 4;
    float AC[4];
#pragma unroll
    for (int i = 0; i < 4; i++) AC[i] = Ag[63 * 65 + cg + i];
#pragma unroll
    for (int j = 0; j < 4; ++j) {
      int row = rr + j * 16;
      size_t g = base + (size_t)(row0 + row) * 1024 + cg;
      uint2 qv = *(const uint2*)(qb + g);
      uint2 kv = *(const uint2*)(kb + g);
      uint2 vv = *(const uint2*)(vb + g);
      float A0 = Ag[row * 65 + cg], A1 = Ag[row * 65 + cg + 1];
      float A2 = Ag[row * 65 + cg + 2], A3 = Ag[row * 65 + cg + 3];
      ushort4 qt;
      qt.x = f2bf(bflo(qv.x) * A0); qt.y = f2bf(bfhi(qv.x) * A1);
      qt.z = f2bf(bflo(qv.y) * A2); qt.w = f2bf(bfhi(qv.y) * A3);
      *(ushort4*)&Qs[row * 72 + cg] = qt;
      *(ushort4*)(qb + g) = qt;  // for pass C
      float R0 = 1.f / A0, R1 = 1.f / A1, R2 = 1.f / A2, R3 = 1.f / A3;
      float kt0 = bflo(kv.x) * R0, kt1 = bfhi(kv.x) * R1;
      float kt2 = bflo(kv.y) * R2, kt3 = bfhi(kv.y) * R3;
      ushort4 kt;
      kt.x = f2bf(kt0); kt.y = f2bf(kt1); kt.z = f2bf(kt2); kt.w = f2bf(kt3);
      *(ushort4*)&Ks[row * 72 + cg] = kt;
      Kht[(cg + 0) * 72 + row] = f2bf(kt0 * AC[0]);
      Kht[(cg + 1) * 72 + row] = f2bf(kt1 * AC[1]);
      Kht[(cg + 2) * 72 + row] = f2bf(kt2 * AC[2]);
      Kht[(cg + 3) * 72 + row] = f2bf(kt3 * AC[3]);
      Vt[(cg + 0) * 72 + row] = (USH)(vv.x & 0xffff);
      Vt[(cg + 1) * 72 + row] = (USH)(vv.x >> 16);
      Vt[(cg + 2) * 72 + row] = (USH)(vv.y & 0xffff);
      Vt[(cg + 3) * 72 + row] = (USH)(vv.y >> 16);
    }
  }
  __syncthreads();

  const int q4 = (ln >> 4) * 4, cc = ln & 15, m16 = ln & 15;

  // ---- MFMA1: P = Q~ @ K~^T ----
  f32x4 pc[4];
#pragma unroll
  for (int n = 0; n < 4; n++) pc[n] = (f32x4){0.f, 0.f, 0.f, 0.f};
#pragma unroll
  for (int ks = 0; ks < 64; ks += 32) {
    bf16x8 aq = *(const bf16x8*)&Qs[(wv * 16 + m16) * 72 + ks + (ln >> 4) * 8];
#pragma unroll
    for (int n = 0; n < 4; ++n) {
      bf16x8 bk = *(const bf16x8*)&Ks[(n * 16 + m16) * 72 + ks + (ln >> 4) * 8];
      pc[n] = __builtin_amdgcn_mfma_f32_16x16x32_bf16(aq, bk, pc[n], 0, 0, 0);
    }
  }
#pragma unroll
  for (int n = 0; n < 4; ++n) {
    int s = n * 16 + cc;
#pragma unroll
    for (int r = 0; r < 4; ++r) {
      int t = wv * 16 + q4 + r;
      Ps[t * 72 + s] = f2bf(s <= t ? pc[n][r] : 0.f);
    }
  }

  // ---- MFMA3 (transposed): S_loc^T[v][k] = sum_s V^T[v][s] * Khat^T[k][s] ----
  f32x4 sc[4];
#pragma unroll
  for (int n = 0; n < 4; n++) sc[n] = (f32x4){0.f, 0.f, 0.f, 0.f};
#pragma unroll
  for (int ks = 0; ks < 64; ks += 32) {
    bf16x8 av = *(const bf16x8*)&Vt[(wv * 16 + m16) * 72 + ks + (ln >> 4) * 8];
#pragma unroll
    for (int n = 0; n < 4; ++n) {
      bf16x8 bk2 = *(const bf16x8*)&Kht[(n * 16 + m16) * 72 + ks + (ln >> 4) * 8];
      sc[n] = __builtin_amdgcn_mfma_f32_16x16x32_bf16(av, bk2, sc[n], 0, 0, 0);
    }
  }
  {
    float* sbp = SB + ((size_t)bh * 32 + ch) * 4096;  // [v][k] f32
#pragma unroll
    for (int n = 0; n < 4; ++n)
#pragma unroll
      for (int r = 0; r < 4; ++r)
        sbp[(wv * 16 + q4 + r) * 64 + n * 16 + cc] = sc[n][r];
  }
  __syncthreads();  // Ps visible

  // ---- MFMA2: O_intra = P @ V ----
  f32x4 oc[4];
#pragma unroll
  for (int n = 0; n < 4; n++) oc[n] = (f32x4){0.f, 0.f, 0.f, 0.f};
#pragma unroll
  for (int ks = 0; ks < 64; ks += 32) {
    bf16x8 ap = *(const bf16x8*)&Ps[(wv * 16 + m16) * 72 + ks + (ln >> 4) * 8];
#pragma unroll
    for (int n = 0; n < 4; ++n) {
      bf16x8 bv = *(const bf16x8*)&Vt[(n * 16 + m16) * 72 + ks + (ln >> 4) * 8];
      oc[n] = __builtin_amdgcn_mfma_f32_16x16x32_bf16(ap, bv, oc[n], 0, 0, 0);
    }
  }
#pragma unroll
  for (int n = 0; n < 4; ++n)
#pragma unroll
    for (int r = 0; r < 4; ++r)
      so[(wv * 16 + q4 + r) * 66 + n * 16 + cc] = f2bf(oc[n][r]);
  __syncthreads();
#pragma unroll
  for (int j = 0; j < 4; ++j) {
    int row = (tid >> 4) + j * 16, cg = (tid & 15) * 4;
    unsigned a = *(const unsigned*)&so[row * 66 + cg];
    unsigned b = *(const unsigned*)&so[row * 66 + cg + 2];
    size_t g = base + (size_t)(row0 + row) * 1024 + cg;
    *(unsigned*)(ob + g) = a;
    *(unsigned*)(ob + g + 2) = b;
  }
}

// ---------------- Pass B: stitch (own kernel; boundary = the sync) ----------------
// 64 blocks (one per bh) x 256 threads. Thread owns (v = tid>>2, k = (tid&3)*16..+15).
// Entry: SB slot = S_loc^T f32; exit: slot head = S_start^T bf16 [64][64].
// Intra-block barrier between slot read and bf16 overwrite (regions alias for v<32).
__global__ __launch_bounds__(256, 1) void gla_stitch(float* __restrict__ SB,
                                                     const float* __restrict__ Dc) {
  const int bh = blockIdx.x;
  const int tid = threadIdx.x;
  const int v = tid >> 2, kq = (tid & 3) * 16;
  float s[16];
#pragma unroll
  for (int i = 0; i < 16; i++) s[i] = 0.f;
  for (int c = 0; c < 32; ++c) {
    float* slot = SB + ((size_t)bh * 32 + c) * 4096;
    float4 l0 = *(float4*)(slot + v * 64 + kq + 0);
    float4 l1 = *(float4*)(slot + v * 64 + kq + 4);
    float4 l2 = *(float4*)(slot + v * 64 + kq + 8);
    float4 l3 = *(float4*)(slot + v * 64 + kq + 12);
    const float* dp = Dc + ((size_t)bh * 32 + c) * 64 + kq;
    float4 d0 = *(const float4*)(dp + 0), d1 = *(const float4*)(dp + 4);
    float4 d2 = *(const float4*)(dp + 8), d3 = *(const float4*)(dp + 12);
    __syncthreads();  // all reads of slot c done before bf16 overwrite
    USH* up = (USH*)slot;  // S_start^T bf16 [64][64] in slot's first 8 KB
    uint4 o0, o1;
    o0.x = (unsigned)f2bf(s[0]) | ((unsigned)f2bf(s[1]) << 16);
    o0.y = (unsigned)f2bf(s[2]) | ((unsigned)f2bf(s[3]) << 16);
    o0.z = (unsigned)f2bf(s[4]) | ((unsigned)f2bf(s[5]) << 16);
    o0.w = (unsigned)f2bf(s[6]) | ((unsigned)f2bf(s[7]) << 16);
    o1.x = (unsigned)f2bf(s[8]) | ((unsigned)f2bf(s[9]) << 16);
    o1.y = (unsigned)f2bf(s[10]) | ((unsigned)f2bf(s[11]) << 16);
    o1.z = (unsigned)f2bf(s[12]) | ((unsigned)f2bf(s[13]) << 16);
    o1.w = (unsigned)f2bf(s[14]) | ((unsigned)f2bf(s[15]) << 16);
    *(uint4*)(up + v * 64 + kq + 0) = o0;
    *(uint4*)(up + v * 64 + kq + 8) = o1;
    s[0] = fmaf(d0.x, s[0], l0.x);  s[1] = fmaf(d0.y, s[1], l0.y);
    s[2] = fmaf(d0.z, s[2], l0.z);  s[3] = fmaf(d0.w, s[3], l0.w);
    s[4] = fmaf(d1.x, s[4], l1.x);  s[5] = fmaf(d1.y, s[5], l1.y);
    s[6] = fmaf(d1.z, s[6], l1.z);  s[7] = fmaf(d1.w, s[7], l1.w);
    s[8] = fmaf(d2.x, s[8], l2.x);  s[9] = fmaf(d2.y, s[9], l2.y);
    s[10] = fmaf(d2.z, s[10], l2.z); s[11] = fmaf(d2.w, s[11], l2.w);
    s[12] = fmaf(d3.x, s[12], l3.x); s[13] = fmaf(d3.y, s[13], l3.y);
    s[14] = fmaf(d3.z, s[14], l3.z); s[15] = fmaf(d3.w, s[15], l3.w);
    __syncthreads();  // bf16 writes done before next c's reads (same-slot only, but cheap)
  }
}

// ---------------- Pass C: o += q~ @ S_start (MFMA), chunks 1..31 ----------------
// S_start^T bf16 read from SB slot heads (written by the stitch).
__global__ __launch_bounds__(256, 4) void gla_corr(
    const USH* __restrict__ qtb, const float* __restrict__ SB, USH* __restrict__ ob) {
  const int bh = blockIdx.y, chn = blockIdx.x + 1;
  const size_t base = (size_t)(bh >> 4) * TSEQ * 1024 + (size_t)(bh & 15) * 64;
  const int trow0 = chn * 64;
  const int tid = threadIdx.x, wv = tid >> 6, ln = tid & 63;
  __shared__ USH qs[64 * 72];
  __shared__ USH sbt[64 * 72];   // S_start^T bf16 [v][k]
  __shared__ float sof[64 * 68]; // o_inter f32 [t][v]
  const USH* sp = (const USH*)(SB + ((size_t)bh * 32 + chn) * 4096);
#pragma unroll
  for (int j = 0; j < 4; ++j) {
    int i = tid + 256 * j;
    int row = i >> 4, cg = (i & 15) * 4;
    *(uint2*)&qs[row * 72 + cg] = *(const uint2*)(qtb + base + (size_t)(trow0 + row) * 1024 + cg);
    *(uint2*)&sbt[row * 72 + cg] = *(const uint2*)(sp + row * 64 + cg);
  }
  __syncthreads();
  const int m16 = ln & 15, q4 = (ln >> 4) * 4, cc = ln & 15;
  f32x4 oc[4];
#pragma unroll
  for (int n = 0; n < 4; n++) oc[n] = (f32x4){0.f, 0.f, 0.f, 0.f};
#pragma unroll
  for (int ks = 0; ks < 64; ks += 32) {
    bf16x8 aq = *(const bf16x8*)&qs[(wv * 16 + m16) * 72 + ks + (ln >> 4) * 8];
#pragma unroll
    for (int n = 0; n < 4; ++n) {
      bf16x8 bv = *(const bf16x8*)&sbt[(n * 16 + m16) * 72 + ks + (ln >> 4) * 8];
      oc[n] = __builtin_amdgcn_mfma_f32_16x16x32_bf16(aq, bv, oc[n], 0, 0, 0);
    }
  }
#pragma unroll
  for (int n = 0; n < 4; ++n)
#pragma unroll
    for (int r = 0; r < 4; ++r)
      sof[(wv * 16 + q4 + r) * 68 + n * 16 + cc] = oc[n][r];
  __syncthreads();
  const int row = tid >> 2, vg = (tid & 3) * 16;
  float4 a0 = *(const float4*)&sof[row * 68 + vg + 0];
  float4 a1 = *(const float4*)&sof[row * 68 + vg + 4];
  float4 a2 = *(const float4*)&sof[row * 68 + vg + 8];
  float4 a3 = *(const float4*)&sof[row * 68 + vg + 12];
  USH* op = ob + base + (size_t)(trow0 + row) * 1024 + vg;
  float ac[16] = {a0.x, a0.y, a0.z, a0.w, a1.x, a1.y, a1.z, a1.w,
                  a2.x, a2.y, a2.z, a2.w, a3.x, a3.y, a3.z, a3.w};
#pragma unroll
  for (int g = 0; g < 4; ++g) {
    ushort4 o4 = *(ushort4*)(op + g * 4);
    o4.x = f2bf(bflo((unsigned)o4.x) + ac[g * 4 + 0]);
    o4.y = f2bf(bflo((unsigned)o4.y) + ac[g * 4 + 1]);
    o4.z = f2bf(bflo((unsigned)o4.z) + ac[g * 4 + 2]);
    o4.w = f2bf(bflo((unsigned)o4.w) + ac[g * 4 + 3]);
    *(ushort4*)(op + g * 4) = o4;
  }
}

extern "C" void kernel_launch(void* const* d_in, const int* in_sizes, int n_in,
                              void* d_out, int out_size, void* d_ws, size_t ws_size,
                              hipStream_t stream) {
  const float* x  = (const float*)d_in[0];
  const float* Wq = (const float*)d_in[1];
  const float* Wk = (const float*)d_in[2];
  const float* Wv = (const float*)d_in[3];
  const float* Wg = (const float*)d_in[4];
  const float* bg = (const float*)d_in[5];
  const float* Wo = (const float*)d_in[6];
  float* out = (float*)d_out;

  // workspace layout (~114.5 MiB; SB's first 8 MiB doubles as WcatT — dead after GEMM1)
  char* ws = (char*)d_ws;
  size_t off = 0;
  auto alloc = [&](size_t bytes) {
    char* p = ws + off;
    off += (bytes + 255) & ~(size_t)255;
    return p;
  };
  USH* xb   = (USH*)alloc((size_t)MM * DM * 2);          // 16 MiB (reused as ob)
  USH* WoT  = (USH*)alloc((size_t)1024 * 1024 * 2);      // 2 MiB
  USH* qb   = (USH*)alloc((size_t)MM * DM * 2);          // 16 MiB
  USH* kb   = (USH*)alloc((size_t)MM * DM * 2);          // 16 MiB
  USH* vb   = (USH*)alloc((size_t)MM * DM * 2);          // 16 MiB
  USH* au   = (USH*)alloc((size_t)MM * DM * 2);          // 16 MiB u16 gate
  float* Dc = (float*)alloc((size_t)64 * 32 * 64 * 4);   // 512 KiB chunk decay (fully used)
  float* SB = (float*)alloc((size_t)64 * 32 * 4096 * 4); // 32 MiB chunk states
  USH* WcatT = (USH*)SB;                                 // aliased (GEMM1 only)
  USH* ob = xb;                                          // xb dead after GEMM1

  // prep: x->bf16, 5 weight transposes
  prep<<<dim3(32, 32, 6), 256, 0, stream>>>(x, Wq, Wk, Wv, Wg, Wo, xb, WcatT, WoT);
  // fused QKV+gate GEMM: (8192x1024) x (1024x4096)
  gemm_bt<1><<<dim3(32, 64), 256, 0, stream>>>(xb, WcatT, 1024, qb, kb, vb, au, bg, nullptr);
  // chunked MFMA scan (intra) + chunk summaries; writes q~ over qb
  gla_chunk<<<2048, 256, 0, stream>>>(qb, kb, vb, au, ob, SB, Dc);
  // stitch: S_loc^T -> S_start^T bf16 (in place, slot heads)
  gla_stitch<<<64, 256, 0, stream>>>(SB, Dc);
  // cross-chunk correction (MFMA, bf16 S_start^T)
  gla_corr<<<dim3(31, 64), 256, 0, stream>>>(qb, SB, ob);
  // output projection: (8192x1024) x (1024x1024) -> f32 d_out
  gemm_bt<0><<<dim3(8, 64), 256, 0, stream>>>(ob, WoT, 1024, nullptr, nullptr, nullptr,
                                              nullptr, nullptr, out);
}